// Round 22
// baseline (70.858 us; speedup 1.0000x reference)
//
#include <hip/hip_runtime.h>
#include <hip/hip_bf16.h>

using f32x4  = __attribute__((ext_vector_type(4))) float;
typedef long long i64f;
typedef unsigned char uchar;

constexpr int BSZ = 8192;
constexpr int DD  = 512;
constexpr int NC  = 100;
constexpr int NT  = 64;                 // 128-row tiles per dim
constexpr int NBLK = NT * (NT + 1) / 2; // 2080 upper-triangle blocks (= 8*260)
constexpr float INV_T = 1.0f / 0.07f;   // analytic shift m = 1/T

// fnrm8 GLOBAL layout: row r = 512 B as 16 chunks x 32 B; within each chunk the
// four 8B slots are permuted s_phys = s_log ^ ((r>>2)&3). LDS staging is an
// identity copy (gload16-compatible) AND frag ds_read_b64 is conflict-free.

static __device__ __forceinline__ void gload16(const void* g, void* l) {
    __builtin_amdgcn_global_load_lds((const __attribute__((address_space(1))) void*)g,
                                     (__attribute__((address_space(3))) void*)l, 16, 0, 0);
}

// asm ds_read: opaque to compiler waitcnt insertion (counted pipeline survives)
#define DSR64(dst, addr, imm) \
    asm volatile("ds_read_b64 %0, %1 offset:%2" : "=v"(dst) : "v"(addr), "i"(imm));

#define DPPADD(v, ctrl) { \
    int _x = __builtin_amdgcn_update_dpp(0, __float_as_int(v), ctrl, 0xf, 0xf, true); \
    v += __int_as_float(_x); }
#define ROWSUM16(v) { DPPADD(v, 0x128) DPPADD(v, 0x124) DPPADD(v, 0x122) DPPADD(v, 0x121) }

// ---------- kernel 1: L2-normalize rows, fp32 -> fp8 e4m3, swizzled layout ----
__global__ __launch_bounds__(256) void norm_rows(const float* __restrict__ feat,
                                                 uchar* __restrict__ fnrm8) {
    const int row = blockIdx.x * 4 + (threadIdx.x >> 6);
    const int l   = threadIdx.x & 63;
    const float4* src = reinterpret_cast<const float4*>(feat + (size_t)row * DD);
    float4 v0 = src[l * 2 + 0];
    float4 v1 = src[l * 2 + 1];
    float ss = v0.x*v0.x + v0.y*v0.y + v0.z*v0.z + v0.w*v0.w
             + v1.x*v1.x + v1.y*v1.y + v1.z*v1.z + v1.w*v1.w;
    #pragma unroll
    for (int m = 32; m >= 1; m >>= 1) ss += __shfl_xor(ss, m, 64);
    const float rn = rsqrtf(ss);
    int w0 = __builtin_amdgcn_cvt_pk_fp8_f32(v0.x * rn, v0.y * rn, 0,  false);
    w0     = __builtin_amdgcn_cvt_pk_fp8_f32(v0.z * rn, v0.w * rn, w0, true);
    int w1 = __builtin_amdgcn_cvt_pk_fp8_f32(v1.x * rn, v1.y * rn, 0,  false);
    w1     = __builtin_amdgcn_cvt_pk_fp8_f32(v1.z * rn, v1.w * rn, w1, true);
    uint2 q; q.x = (unsigned)w0; q.y = (unsigned)w1;
    // lane l = logical 8B piece (kt = l>>2, s_log = l&3); apply layout permutation
    const int off = ((l >> 2) << 5) + ((((l & 3) ^ ((row >> 2) & 3))) << 3);
    *reinterpret_cast<uint2*>(fnrm8 + (size_t)row * DD + off) = q;
}

// ---------- kernel 2: per-class g_c via ballot scan -> cls_val[c], counts[c] ----
// (identity verified R13-R15) sum_i spos_i/npos_i = (||g_c||^2-n)/(T(n-1))
__global__ __launch_bounds__(256) void gsum(const uchar* __restrict__ fnrm8,
                                            const int* __restrict__ labels,
                                            float* __restrict__ cls_val,
                                            int* __restrict__ counts) {
    __shared__ int   slab[BSZ];          // 32 KB
    __shared__ float gred[4][DD];        // 8 KB
    __shared__ float sq4[4];
    __shared__ int   cc[4];

    const int t = threadIdx.x, w = t >> 6, lam = t & 63;
    for (int i = t; i < BSZ; i += 256) slab[i] = labels[i];
    __syncthreads();

    const int c = blockIdx.x;
    float a[8] = {0.f,0.f,0.f,0.f,0.f,0.f,0.f,0.f};
    int cnt = 0;
    const int kt_off = (lam >> 2) << 5;
    for (int base = w * 2048; base < (w + 1) * 2048; base += 64) {
        const unsigned long long m0 = __ballot(slab[base + lam] == c);
        cnt += (int)__popcll(m0);
        unsigned long long m = m0;
        while (m) {
            const int j = __ffsll((long long)m) - 1; m &= m - 1;
            const int r = base + j;
            const int off = kt_off + ((((lam & 3) ^ ((r >> 2) & 3))) << 3);
            const uint2 q = *reinterpret_cast<const uint2*>(
                fnrm8 + (size_t)r * DD + off);
            a[0] += __builtin_amdgcn_cvt_f32_fp8(q.x, 0);
            a[1] += __builtin_amdgcn_cvt_f32_fp8(q.x, 1);
            a[2] += __builtin_amdgcn_cvt_f32_fp8(q.x, 2);
            a[3] += __builtin_amdgcn_cvt_f32_fp8(q.x, 3);
            a[4] += __builtin_amdgcn_cvt_f32_fp8(q.y, 0);
            a[5] += __builtin_amdgcn_cvt_f32_fp8(q.y, 1);
            a[6] += __builtin_amdgcn_cvt_f32_fp8(q.y, 2);
            a[7] += __builtin_amdgcn_cvt_f32_fp8(q.y, 3);
        }
    }
    #pragma unroll
    for (int d = 0; d < 8; ++d) gred[w][lam * 8 + d] = a[d];
    if (lam == 0) cc[w] = cnt;
    __syncthreads();

    const float g0 = gred[0][t] + gred[1][t] + gred[2][t] + gred[3][t];
    const float g1 = gred[0][t + 256] + gred[1][t + 256] + gred[2][t + 256] + gred[3][t + 256];
    float sq = g0 * g0 + g1 * g1;
    #pragma unroll
    for (int m = 32; m >= 1; m >>= 1) sq += __shfl_xor(sq, m, 64);
    if (lam == 0) sq4[w] = sq;
    __syncthreads();
    if (t == 0) {
        const float gsq = sq4[0] + sq4[1] + sq4[2] + sq4[3];
        const int   n   = cc[0] + cc[1] + cc[2] + cc[3];
        counts[c]  = n;
        cls_val[c] = (n >= 2) ? (gsq - (float)n) * INV_T / (float)(n - 1) : 0.f;
    }
}

// ---------- kernel 3: fp8 sim-GEMM -> denom. WAVE-PRIVATE pipelines ----------
// 4 waves (2x2), wave = 64x64 out (acc[4][4] = 64 AGPR). BK=64, 8 K-iters.
// Each wave stages ITS OWN A-half (64x64B) + B-half into a private 16 KB LDS
// region (2 bufs x 8 KB). ZERO barriers in the K-loop: the only wait is the
// wave's own vmcnt(0) for loads issued one full MFMA-bound iteration earlier.
// 64 KB LDS -> 2 blocks/CU; (256,2) -> 256 regs/wave, spill impossible.
__global__ __launch_bounds__(256, 2) void supcon_main(const uchar* __restrict__ fnrm8,
                                                      float* __restrict__ part_denom) {
    __shared__ __align__(16) uchar smem[4 * 16384];    // 64 KB: wave w at w*16384

    // bijective XCD-contiguous swizzle (2080 = 8 * 260) + upper-tri decode
    const int raw = blockIdx.x;
    const int bid = (raw & 7) * 260 + (raw >> 3);
    int rt = 0, rem = bid;
    while (rem >= NT - rt) { rem -= NT - rt; ++rt; }
    const int ct = rt + rem;
    const bool diag = (ct == rt);

    const int t  = threadIdx.x;
    const int l  = t & 63;
    const int lr = l & 15, grp = l >> 4;
    const int w  = t >> 6;
    const int wr = w >> 1, wc = w & 1;    // 2x2 wave grid; wave = 64x64 out
    const int rowBase = rt * 128, colBase = ct * 128;

    // per-lane staging base: lane l covers rows (l>>2)+j*16 (j=0..3), 16B chunk
    // q = l&3 of each 64B row-slice. Identity copy of the pre-swizzled layout.
    const uchar* g8A = fnrm8 + (size_t)(rowBase + wr * 64 + (l >> 2)) * DD + (l & 3) * 16;
    const uchar* g8B = fnrm8 + (size_t)(colBase + wc * 64 + (l >> 2)) * DD + (l & 3) * 16;
    uchar* WS = smem + w * 16384;         // this wave's private region
    const int l16 = l * 16;

    #define STG(kt, b) { \
        gload16(g8A + (kt) * 64,           WS + (b) * 8192 +        l16); \
        gload16(g8A + (kt) * 64 + 16 * DD, WS + (b) * 8192 + 1024 + l16); \
        gload16(g8A + (kt) * 64 + 32 * DD, WS + (b) * 8192 + 2048 + l16); \
        gload16(g8A + (kt) * 64 + 48 * DD, WS + (b) * 8192 + 3072 + l16); \
        gload16(g8B + (kt) * 64,           WS + (b) * 8192 + 4096 + l16); \
        gload16(g8B + (kt) * 64 + 16 * DD, WS + (b) * 8192 + 5120 + l16); \
        gload16(g8B + (kt) * 64 + 32 * DD, WS + (b) * 8192 + 6144 + l16); \
        gload16(g8B + (kt) * 64 + 48 * DD, WS + (b) * 8192 + 7168 + l16); }

    // ds_read byte addrs (loop-invariant); buf/frag are immediates in the
    // unrolled loop. frag (fa,ks): local row = fa*16+lr -> byte fa*1024+lr*64;
    // slot = grp ^ ((row>>2)&3) = grp ^ ((lr>>2)&3) (row base multiple of 16).
    const int slot = grp ^ ((lr >> 2) & 3);
    int va[2], vb[2];
    #pragma unroll
    for (int ks = 0; ks < 2; ++ks) {
        va[ks] = w * 16384 + lr * 64 + ks * 32 + slot * 8;
        vb[ks] = w * 16384 + 4096 + lr * 64 + ks * 32 + slot * 8;
    }

    f32x4 acc[4][4];
    #pragma unroll
    for (int i = 0; i < 4; ++i)
        #pragma unroll
        for (int j = 0; j < 4; ++j) acc[i][j] = f32x4{0.f, 0.f, 0.f, 0.f};

    STG(0, 0)

    #pragma unroll
    for (int it = 0; it < 8; ++it) {
        const int b = it & 1;
        asm volatile("s_waitcnt vmcnt(0)" ::: "memory");  // own loads: tile it landed
        if (it < 7) STG(it + 1, b ^ 1)                    // full-iter issue->wait gap

        #pragma unroll
        for (int ks = 0; ks < 2; ++ks) {
            i64f aF[4], bF[4];
            DSR64(aF[0], va[ks], (b * 8192) + 0)     DSR64(aF[1], va[ks], (b * 8192) + 1024)
            DSR64(aF[2], va[ks], (b * 8192) + 2048)  DSR64(aF[3], va[ks], (b * 8192) + 3072)
            DSR64(bF[0], vb[ks], (b * 8192) + 0)     DSR64(bF[1], vb[ks], (b * 8192) + 1024)
            DSR64(bF[2], vb[ks], (b * 8192) + 2048)  DSR64(bF[3], vb[ks], (b * 8192) + 3072)
            asm volatile("s_waitcnt lgkmcnt(0)");
            __builtin_amdgcn_sched_barrier(0);   // rule #18
            __builtin_amdgcn_s_setprio(1);
            #pragma unroll
            for (int fa = 0; fa < 4; ++fa)
                #pragma unroll
                for (int fb = 0; fb < 4; ++fb)
                    acc[fa][fb] = __builtin_amdgcn_mfma_f32_16x16x32_fp8_fp8(
                        aF[fa], bF[fb], acc[fa][fb], 0, 0, 0);
            __builtin_amdgcn_s_setprio(0);
        }
    }
    #undef STG

    // ---- lean epilogue: e = exp(sim - m); row & col denom sums only ----
    __syncthreads();                      // all waves done with private regions
    float* red  = reinterpret_cast<float*>(smem);          // [128 row][2 wc]
    float* cred = reinterpret_cast<float*>(smem) + 256;    // [128 col][2 wr]

    float cdv[4] = {0.f, 0.f, 0.f, 0.f};
    #pragma unroll
    for (int fa = 0; fa < 4; ++fa) {
        #pragma unroll
        for (int r = 0; r < 4; ++r) {
            const int row_l = wr * 64 + fa * 16 + grp * 4 + r;
            const int grow  = rowBase + row_l;
            float dsum = 0.f;
            #pragma unroll
            for (int fb = 0; fb < 4; ++fb) {
                const int col_l = wc * 64 + fb * 16 + lr;
                const float e  = __expf(acc[fa][fb][r] * INV_T - INV_T);
                const float ev = ((colBase + col_l) != grow) ? e : 0.f;
                dsum += ev; cdv[fb] += ev;
            }
            ROWSUM16(dsum)
            if (lr == 0) red[row_l * 2 + wc] = dsum;
        }
    }
    #pragma unroll
    for (int fb = 0; fb < 4; ++fb) {      // col-side: reduce over grp lanes
        cdv[fb] += __shfl_xor(cdv[fb], 16, 64);
        cdv[fb] += __shfl_xor(cdv[fb], 32, 64);
    }
    if (grp == 0) {
        #pragma unroll
        for (int fb = 0; fb < 4; ++fb)
            cred[(wc * 64 + fb * 16 + lr) * 2 + wr] = cdv[fb];
    }
    __syncthreads();
    if (t < 128) {                        // row-side: combine 2 wc halves
        const float d = red[t * 2] + red[t * 2 + 1];
        part_denom[(size_t)ct * BSZ + rowBase + t] = d;
    } else if (!diag) {                   // col-side: combine 2 wr halves
        const int c = t - 128;
        const float d = cred[c * 2] + cred[c * 2 + 1];
        part_denom[(size_t)rt * BSZ + colBase + c] = d;
    }
}

// ---------- kernel 4: per-row lse + per-block scalar partials ----------
__global__ __launch_bounds__(256) void row_finalize(const float* __restrict__ part_denom,
                                                    const int* __restrict__ counts,
                                                    const int* __restrict__ labels,
                                                    float* __restrict__ bsum,
                                                    float* __restrict__ bval) {
    __shared__ float s4[4], v4[4];
    const int t = threadIdx.x;
    const int row = blockIdx.x * 256 + t;
    float denom = 0.f;
    for (int k = 0; k < NT; ++k) denom += part_denom[(size_t)k * BSZ + row];
    const bool valid = counts[labels[row]] >= 2;
    float s = valid ? (INV_T + logf(denom + 1e-12f)) : 0.f;
    float v = valid ? 1.f : 0.f;
    #pragma unroll
    for (int m = 32; m >= 1; m >>= 1) { s += __shfl_xor(s, m, 64); v += __shfl_xor(v, m, 64); }
    if ((t & 63) == 0) { s4[t >> 6] = s; v4[t >> 6] = v; }
    __syncthreads();
    if (t == 0) {
        bsum[blockIdx.x] = s4[0] + s4[1] + s4[2] + s4[3];
        bval[blockIdx.x] = v4[0] + v4[1] + v4[2] + v4[3];
    }
}

// ---------- kernel 5: final scalar ----------
__global__ __launch_bounds__(128) void final_reduce(const float* __restrict__ bsum,
                                                    const float* __restrict__ bval,
                                                    const float* __restrict__ cls_val,
                                                    float* __restrict__ out) {
    __shared__ float r2[2], q2[2], p2[2];
    const int t = threadIdx.x;
    float s = (t < 32) ? bsum[t] : 0.f;
    float v = (t < 32) ? bval[t] : 0.f;
    float p = (t < NC) ? cls_val[t] : 0.f;
    #pragma unroll
    for (int m = 32; m >= 1; m >>= 1) {
        s += __shfl_xor(s, m, 64); v += __shfl_xor(v, m, 64); p += __shfl_xor(p, m, 64);
    }
    if ((t & 63) == 0) { r2[t >> 6] = s; q2[t >> 6] = v; p2[t >> 6] = p; }
    __syncthreads();
    if (t == 0) {
        const float S = r2[0] + r2[1], V = q2[0] + q2[1], SP = p2[0] + p2[1];
        out[0] = -(SP - S) / fmaxf(V, 1.f);
    }
}

extern "C" void kernel_launch(void* const* d_in, const int* in_sizes, int n_in,
                              void* d_out, int out_size, void* d_ws, size_t ws_size,
                              hipStream_t stream) {
    const float* feat   = (const float*)d_in[0];
    const int*   labels = (const int*)d_in[1];
    float*       out    = (float*)d_out;

    char* ws = (char*)d_ws;
    uchar*  fnrm8      = (uchar*)ws;   ws += (size_t)BSZ * DD;       // 4 MB fp8
    float*  part_denom = (float*)ws;   ws += (size_t)NT * BSZ * 4;   // 2 MB
    float*  cls_val    = (float*)ws;   ws += NC * 4 + 288;
    int*    counts     = (int*)ws;     ws += NC * 4 + 288;
    float*  bsum       = (float*)ws;   ws += 32 * 4;
    float*  bval       = (float*)ws;   ws += 32 * 4;

    hipLaunchKernelGGL(norm_rows,    dim3(BSZ / 4), dim3(256),  0, stream, feat, fnrm8);
    hipLaunchKernelGGL(gsum,         dim3(NC),      dim3(256),  0, stream,
                       fnrm8, labels, cls_val, counts);
    hipLaunchKernelGGL(supcon_main,  dim3(NBLK),    dim3(256),  0, stream,
                       fnrm8, part_denom);
    hipLaunchKernelGGL(row_finalize, dim3(BSZ/256), dim3(256),  0, stream,
                       part_denom, counts, labels, bsum, bval);
    hipLaunchKernelGGL(final_reduce, dim3(1),       dim3(128),  0, stream,
                       bsum, bval, cls_val, out);
}

// Round 23
// 60.929 us; speedup vs baseline: 1.1630x; 1.1630x over previous
//
#include <hip/hip_runtime.h>
#include <hip/hip_bf16.h>

using f32x4  = __attribute__((ext_vector_type(4))) float;
typedef long long i64f;
typedef unsigned char uchar;

constexpr int BSZ = 8192;
constexpr int DD  = 512;
constexpr int NC  = 100;
constexpr int NT  = 64;                 // 128-row tiles per dim
constexpr int NBLK = NT * (NT + 1) / 2; // 2080 upper-triangle blocks (= 8*260)
constexpr float INV_T = 1.0f / 0.07f;   // analytic shift m = 1/T

// fnrm8 GLOBAL layout: row r = 512 B as 16 chunks x 32 B; within each chunk the
// four 8B slots are permuted s_phys = s_log ^ ((r>>2)&3). LDS staging is an
// identity copy (gload16-compatible) AND frag ds_read_b64 is conflict-free.

static __device__ __forceinline__ void gload16(const void* g, void* l) {
    __builtin_amdgcn_global_load_lds((const __attribute__((address_space(1))) void*)g,
                                     (__attribute__((address_space(3))) void*)l, 16, 0, 0);
}

// asm ds_read: opaque to compiler waitcnt insertion (counted pipeline survives)
#define DSR64(dst, addr, imm) \
    asm volatile("ds_read_b64 %0, %1 offset:%2" : "=v"(dst) : "v"(addr), "i"(imm));

#define DPPADD(v, ctrl) { \
    int _x = __builtin_amdgcn_update_dpp(0, __float_as_int(v), ctrl, 0xf, 0xf, true); \
    v += __int_as_float(_x); }
#define ROWSUM16(v) { DPPADD(v, 0x128) DPPADD(v, 0x124) DPPADD(v, 0x122) DPPADD(v, 0x121) }

// ---------- kernel 1: L2-normalize rows, fp32 -> fp8 e4m3, swizzled layout ----
__global__ __launch_bounds__(256) void norm_rows(const float* __restrict__ feat,
                                                 uchar* __restrict__ fnrm8) {
    const int row = blockIdx.x * 4 + (threadIdx.x >> 6);
    const int l   = threadIdx.x & 63;
    const float4* src = reinterpret_cast<const float4*>(feat + (size_t)row * DD);
    float4 v0 = src[l * 2 + 0];
    float4 v1 = src[l * 2 + 1];
    float ss = v0.x*v0.x + v0.y*v0.y + v0.z*v0.z + v0.w*v0.w
             + v1.x*v1.x + v1.y*v1.y + v1.z*v1.z + v1.w*v1.w;
    #pragma unroll
    for (int m = 32; m >= 1; m >>= 1) ss += __shfl_xor(ss, m, 64);
    const float rn = rsqrtf(ss);
    int w0 = __builtin_amdgcn_cvt_pk_fp8_f32(v0.x * rn, v0.y * rn, 0,  false);
    w0     = __builtin_amdgcn_cvt_pk_fp8_f32(v0.z * rn, v0.w * rn, w0, true);
    int w1 = __builtin_amdgcn_cvt_pk_fp8_f32(v1.x * rn, v1.y * rn, 0,  false);
    w1     = __builtin_amdgcn_cvt_pk_fp8_f32(v1.z * rn, v1.w * rn, w1, true);
    uint2 q; q.x = (unsigned)w0; q.y = (unsigned)w1;
    // lane l = logical 8B piece (kt = l>>2, s_log = l&3); apply layout permutation
    const int off = ((l >> 2) << 5) + ((((l & 3) ^ ((row >> 2) & 3))) << 3);
    *reinterpret_cast<uint2*>(fnrm8 + (size_t)row * DD + off) = q;
}

// ---------- kernel 2: per-class g_c via ballot scan -> cls_val[c], counts[c] ----
// (identity verified R13-R15) sum_i spos_i/npos_i = (||g_c||^2-n)/(T(n-1))
__global__ __launch_bounds__(256) void gsum(const uchar* __restrict__ fnrm8,
                                            const int* __restrict__ labels,
                                            float* __restrict__ cls_val,
                                            int* __restrict__ counts) {
    __shared__ int   slab[BSZ];          // 32 KB
    __shared__ float gred[4][DD];        // 8 KB
    __shared__ float sq4[4];
    __shared__ int   cc[4];

    const int t = threadIdx.x, w = t >> 6, lam = t & 63;
    for (int i = t; i < BSZ; i += 256) slab[i] = labels[i];
    __syncthreads();

    const int c = blockIdx.x;
    float a[8] = {0.f,0.f,0.f,0.f,0.f,0.f,0.f,0.f};
    int cnt = 0;
    const int kt_off = (lam >> 2) << 5;
    for (int base = w * 2048; base < (w + 1) * 2048; base += 64) {
        const unsigned long long m0 = __ballot(slab[base + lam] == c);
        cnt += (int)__popcll(m0);
        unsigned long long m = m0;
        while (m) {
            const int j = __ffsll((long long)m) - 1; m &= m - 1;
            const int r = base + j;
            const int off = kt_off + ((((lam & 3) ^ ((r >> 2) & 3))) << 3);
            const uint2 q = *reinterpret_cast<const uint2*>(
                fnrm8 + (size_t)r * DD + off);
            a[0] += __builtin_amdgcn_cvt_f32_fp8(q.x, 0);
            a[1] += __builtin_amdgcn_cvt_f32_fp8(q.x, 1);
            a[2] += __builtin_amdgcn_cvt_f32_fp8(q.x, 2);
            a[3] += __builtin_amdgcn_cvt_f32_fp8(q.x, 3);
            a[4] += __builtin_amdgcn_cvt_f32_fp8(q.y, 0);
            a[5] += __builtin_amdgcn_cvt_f32_fp8(q.y, 1);
            a[6] += __builtin_amdgcn_cvt_f32_fp8(q.y, 2);
            a[7] += __builtin_amdgcn_cvt_f32_fp8(q.y, 3);
        }
    }
    #pragma unroll
    for (int d = 0; d < 8; ++d) gred[w][lam * 8 + d] = a[d];
    if (lam == 0) cc[w] = cnt;
    __syncthreads();

    const float g0 = gred[0][t] + gred[1][t] + gred[2][t] + gred[3][t];
    const float g1 = gred[0][t + 256] + gred[1][t + 256] + gred[2][t + 256] + gred[3][t + 256];
    float sq = g0 * g0 + g1 * g1;
    #pragma unroll
    for (int m = 32; m >= 1; m >>= 1) sq += __shfl_xor(sq, m, 64);
    if (lam == 0) sq4[w] = sq;
    __syncthreads();
    if (t == 0) {
        const float gsq = sq4[0] + sq4[1] + sq4[2] + sq4[3];
        const int   n   = cc[0] + cc[1] + cc[2] + cc[3];
        counts[c]  = n;
        cls_val[c] = (n >= 2) ? (gsq - (float)n) * INV_T / (float)(n - 1) : 0.f;
    }
}

// ---------- kernel 3: fp8 sim-GEMM -> denom. BK=64, 8 iters, 4 blocks/CU ------
// 4 waves (2x2), wave = 64x64 out (acc[4][4] = 64 AGPR). BK=64 (fp8), 8 K-iters.
// 2 LDS bufs x 16KB (A 8K + B 8K) = 32 KB -> 4 blocks/CU. Per iter: vmcnt(0)+
// barrier (tile it landed; staged a full iter ago) -> STG(it+1, buf^1) ->
// 2 x {8 ds_read_b64, lgkm0, 16 MFMA}.
__global__ __launch_bounds__(256, 4) void supcon_main(const uchar* __restrict__ fnrm8,
                                                      float* __restrict__ part_denom) {
    __shared__ __align__(16) uchar smem[2 * 16384];    // 32 KB: buf b at b*16384B

    // bijective XCD-contiguous swizzle (2080 = 8 * 260) + upper-tri decode
    const int raw = blockIdx.x;
    const int bid = (raw & 7) * 260 + (raw >> 3);
    int rt = 0, rem = bid;
    while (rem >= NT - rt) { rem -= NT - rt; ++rt; }
    const int ct = rt + rem;
    const bool diag = (ct == rt);

    const int t  = threadIdx.x;
    const int l  = t & 63;
    const int lr = l & 15, grp = l >> 4;
    const int w  = t >> 6;
    const int wr = w >> 1, wc = w & 1;    // 2x2 wave grid; wave = 64x64 out
    const int rowBase = rt * 128, colBase = ct * 128;

    // staging: identity copy of the physical (pre-swizzled) layout.
    // tile/matrix = [128 rows][64 B] = 8KB = 512 16B-chunks; thread t owns
    // chunks t (rows 0-63) and t+256 (rows 64-127): row = t>>2, q = t&3.
    const int srow = t >> 2;
    const uchar* g8A = fnrm8 + (size_t)(rowBase + srow) * DD + (t & 3) * 16;
    const uchar* g8B = fnrm8 + (size_t)(colBase + srow) * DD + (t & 3) * 16;
    uchar* S = smem;
    const int t16 = t * 16;

    #define STG(kt, b) { \
        gload16(g8A + (kt) * 64,           S + (b) * 16384 +         t16); \
        gload16(g8A + (kt) * 64 + 64 * DD, S + (b) * 16384 +  4096 + t16); \
        gload16(g8B + (kt) * 64,           S + (b) * 16384 +  8192 + t16); \
        gload16(g8B + (kt) * 64 + 64 * DD, S + (b) * 16384 + 12288 + t16); }

    // ds_read byte addrs (loop-invariant); buf/frag are immediates.
    // frag (fa, ks): row = wr*64 + fa*16 + lr; addr = row*64 + ks*32 + slot*8,
    // slot = grp ^ ((row>>2)&3) = grp ^ ((lr>>2)&3). fa adds 1024B (16 rows).
    const int slot = grp ^ ((lr >> 2) & 3);
    int va[2], vb[2];
    #pragma unroll
    for (int ks = 0; ks < 2; ++ks) {
        va[ks] = (wr * 64 + lr) * 64 + ks * 32 + slot * 8;
        vb[ks] = 8192 + (wc * 64 + lr) * 64 + ks * 32 + slot * 8;
    }

    f32x4 acc[4][4];
    #pragma unroll
    for (int i = 0; i < 4; ++i)
        #pragma unroll
        for (int j = 0; j < 4; ++j) acc[i][j] = f32x4{0.f, 0.f, 0.f, 0.f};

    STG(0, 0)

    #pragma unroll
    for (int it = 0; it < 8; ++it) {
        const int b = it & 1;
        asm volatile("s_waitcnt vmcnt(0)" ::: "memory");  // tile it landed
        __builtin_amdgcn_s_barrier();                     // ...for all waves
        if (it < 7) STG(it + 1, b ^ 1)                    // full-iter issue->wait gap

        #pragma unroll
        for (int ks = 0; ks < 2; ++ks) {
            i64f aF[4], bF[4];
            DSR64(aF[0], va[ks], (b * 16384) + 0)     DSR64(aF[1], va[ks], (b * 16384) + 1024)
            DSR64(aF[2], va[ks], (b * 16384) + 2048)  DSR64(aF[3], va[ks], (b * 16384) + 3072)
            DSR64(bF[0], vb[ks], (b * 16384) + 0)     DSR64(bF[1], vb[ks], (b * 16384) + 1024)
            DSR64(bF[2], vb[ks], (b * 16384) + 2048)  DSR64(bF[3], vb[ks], (b * 16384) + 3072)
            asm volatile("s_waitcnt lgkmcnt(0)");
            __builtin_amdgcn_sched_barrier(0);   // rule #18
            __builtin_amdgcn_s_setprio(1);
            #pragma unroll
            for (int fa = 0; fa < 4; ++fa)
                #pragma unroll
                for (int fb = 0; fb < 4; ++fb)
                    acc[fa][fb] = __builtin_amdgcn_mfma_f32_16x16x32_fp8_fp8(
                        aF[fa], bF[fb], acc[fa][fb], 0, 0, 0);
            __builtin_amdgcn_s_setprio(0);
        }
    }
    #undef STG

    // ---- lean epilogue: e = exp(sim - m); row & col denom sums only ----
    __syncthreads();
    float* red  = reinterpret_cast<float*>(smem);          // [128 row][2 wc]
    float* cred = reinterpret_cast<float*>(smem) + 256;    // [128 col][2 wr]

    float cdv[4] = {0.f, 0.f, 0.f, 0.f};
    #pragma unroll
    for (int fa = 0; fa < 4; ++fa) {
        #pragma unroll
        for (int r = 0; r < 4; ++r) {
            const int row_l = wr * 64 + fa * 16 + grp * 4 + r;
            const int grow  = rowBase + row_l;
            float dsum = 0.f;
            #pragma unroll
            for (int fb = 0; fb < 4; ++fb) {
                const int col_l = wc * 64 + fb * 16 + lr;
                const float e  = __expf(acc[fa][fb][r] * INV_T - INV_T);
                const float ev = ((colBase + col_l) != grow) ? e : 0.f;
                dsum += ev; cdv[fb] += ev;
            }
            ROWSUM16(dsum)
            if (lr == 0) red[row_l * 2 + wc] = dsum;
        }
    }
    #pragma unroll
    for (int fb = 0; fb < 4; ++fb) {      // col-side: reduce over grp lanes
        cdv[fb] += __shfl_xor(cdv[fb], 16, 64);
        cdv[fb] += __shfl_xor(cdv[fb], 32, 64);
    }
    if (grp == 0) {
        #pragma unroll
        for (int fb = 0; fb < 4; ++fb)
            cred[(wc * 64 + fb * 16 + lr) * 2 + wr] = cdv[fb];
    }
    __syncthreads();
    if (t < 128) {                        // row-side: combine 2 wc halves
        const float d = red[t * 2] + red[t * 2 + 1];
        part_denom[(size_t)ct * BSZ + rowBase + t] = d;
    } else if (!diag) {                   // col-side: combine 2 wr halves
        const int c = t - 128;
        const float d = cred[c * 2] + cred[c * 2 + 1];
        part_denom[(size_t)rt * BSZ + colBase + c] = d;
    }
}

// ---------- kernel 4: per-row lse + per-block scalar partials ----------
__global__ __launch_bounds__(256) void row_finalize(const float* __restrict__ part_denom,
                                                    const int* __restrict__ counts,
                                                    const int* __restrict__ labels,
                                                    float* __restrict__ bsum,
                                                    float* __restrict__ bval) {
    __shared__ float s4[4], v4[4];
    const int t = threadIdx.x;
    const int row = blockIdx.x * 256 + t;
    float denom = 0.f;
    for (int k = 0; k < NT; ++k) denom += part_denom[(size_t)k * BSZ + row];
    const bool valid = counts[labels[row]] >= 2;
    float s = valid ? (INV_T + logf(denom + 1e-12f)) : 0.f;
    float v = valid ? 1.f : 0.f;
    #pragma unroll
    for (int m = 32; m >= 1; m >>= 1) { s += __shfl_xor(s, m, 64); v += __shfl_xor(v, m, 64); }
    if ((t & 63) == 0) { s4[t >> 6] = s; v4[t >> 6] = v; }
    __syncthreads();
    if (t == 0) {
        bsum[blockIdx.x] = s4[0] + s4[1] + s4[2] + s4[3];
        bval[blockIdx.x] = v4[0] + v4[1] + v4[2] + v4[3];
    }
}

// ---------- kernel 5: final scalar ----------
__global__ __launch_bounds__(128) void final_reduce(const float* __restrict__ bsum,
                                                    const float* __restrict__ bval,
                                                    const float* __restrict__ cls_val,
                                                    float* __restrict__ out) {
    __shared__ float r2[2], q2[2], p2[2];
    const int t = threadIdx.x;
    float s = (t < 32) ? bsum[t] : 0.f;
    float v = (t < 32) ? bval[t] : 0.f;
    float p = (t < NC) ? cls_val[t] : 0.f;
    #pragma unroll
    for (int m = 32; m >= 1; m >>= 1) {
        s += __shfl_xor(s, m, 64); v += __shfl_xor(v, m, 64); p += __shfl_xor(p, m, 64);
    }
    if ((t & 63) == 0) { r2[t >> 6] = s; q2[t >> 6] = v; p2[t >> 6] = p; }
    __syncthreads();
    if (t == 0) {
        const float S = r2[0] + r2[1], V = q2[0] + q2[1], SP = p2[0] + p2[1];
        out[0] = -(SP - S) / fmaxf(V, 1.f);
    }
}

extern "C" void kernel_launch(void* const* d_in, const int* in_sizes, int n_in,
                              void* d_out, int out_size, void* d_ws, size_t ws_size,
                              hipStream_t stream) {
    const float* feat   = (const float*)d_in[0];
    const int*   labels = (const int*)d_in[1];
    float*       out    = (float*)d_out;

    char* ws = (char*)d_ws;
    uchar*  fnrm8      = (uchar*)ws;   ws += (size_t)BSZ * DD;       // 4 MB fp8
    float*  part_denom = (float*)ws;   ws += (size_t)NT * BSZ * 4;   // 2 MB
    float*  cls_val    = (float*)ws;   ws += NC * 4 + 288;
    int*    counts     = (int*)ws;     ws += NC * 4 + 288;
    float*  bsum       = (float*)ws;   ws += 32 * 4;
    float*  bval       = (float*)ws;   ws += 32 * 4;

    hipLaunchKernelGGL(norm_rows,    dim3(BSZ / 4), dim3(256),  0, stream, feat, fnrm8);
    hipLaunchKernelGGL(gsum,         dim3(NC),      dim3(256),  0, stream,
                       fnrm8, labels, cls_val, counts);
    hipLaunchKernelGGL(supcon_main,  dim3(NBLK),    dim3(256),  0, stream,
                       fnrm8, part_denom);
    hipLaunchKernelGGL(row_finalize, dim3(BSZ/256), dim3(256),  0, stream,
                       part_denom, counts, labels, bsum, bval);
    hipLaunchKernelGGL(final_reduce, dim3(1),       dim3(128),  0, stream,
                       bsum, bval, cls_val, out);
}